// Round 8
// baseline (79.725 us; speedup 1.0000x reference)
//
#include <hip/hip_runtime.h>
#include <hip/hip_bf16.h>

typedef __bf16 bf16x8 __attribute__((ext_vector_type(8)));
typedef float f32x4 __attribute__((ext_vector_type(4)));

#define NUM_TEAMS 100000
#define NUM_MATCHES 1000000
#define LOG2E 1.4426950408889634f
#define NWG 3126            // 1563 team-tiles x 2 hcol-halves
#define XQ 390              // NWG/8
#define XR 6                // NWG%8

__device__ __forceinline__ unsigned short f2bf(float x) {
    __hip_bfloat16 h = __float2bfloat16(x);
    return reinterpret_cast<unsigned short&>(h);
}
// single-instruction packed f32x2 -> bf16x2. No builtin on gfx950 (m240) -> asm.
__device__ __forceinline__ unsigned int cvtpk(float a, float b) {
    unsigned int r;
    asm("v_cvt_pk_bf16_f32 %0, %1, %2" : "=v"(r) : "v"(a), "v"(b));
    return r;
}
__device__ __forceinline__ float exp2_(float x) {
    float r; asm("v_exp_f32 %0, %1" : "=v"(r) : "v"(x)); return r;
}
__device__ __forceinline__ float rcp_(float x) {
    float r; asm("v_rcp_f32 %0, %1" : "=v"(r) : "v"(x)); return r;
}

// ---------------- prep: pack W fragment-major bf16; biases pre-scaled by log2e ----------------
// Wpk u16 index = G*16384 + gate*4096 + ks*512 + l4*128 + l15*8 + e
//   holds W[row = gate*128 + G*16 + l15][k = ks*32 + l4*8 + e]  (W = [W_ih | W_hh])
__global__ __launch_bounds__(256) void prep_kernel(
    const float* __restrict__ W_ih, const float* __restrict__ W_hh,
    const float* __restrict__ b_ih, const float* __restrict__ b_hh,
    unsigned short* __restrict__ Wpk, float* __restrict__ biasc)
{
    int gid = blockIdx.x * 256 + threadIdx.x;   // 131072 bf16 elements
    int e = gid & 7;
    int chunk = gid >> 3;                        // 16B chunk id
    int l15 = chunk & 15;
    int l4 = (chunk >> 4) & 3;
    int rest = chunk >> 6;
    int ks = rest & 7;
    int gate = (rest >> 3) & 3;
    int G = rest >> 5;
    int row = gate * 128 + G * 16 + l15;
    int k = ks * 32 + l4 * 8 + e;
    float v = (k < 128) ? W_ih[row * 128 + k] : W_hh[row * 128 + (k - 128)];
    Wpk[gid] = f2bf(v);
    if (gid < 512) {
        float b = b_ih[gid] + b_hh[gid];
        float scale = ((gid >> 7) == 2) ? (2.0f * LOG2E) : (-LOG2E);
        biasc[gid] = b * scale;
    }
}

// ---------------- LSTM + fused partial proj ----------------
// Round-7 skeleton (best measured: short blocks, 4 independent blocks/CU,
// 16 waves/CU; regs exactly 64 VGPR + 64 AGPR = 128/wave). Round-8 polish,
// live-range-neutral:
//  (c) act algebra: sigmoid(a)*tanh(b) = (E-1)*rcp((1+I)(1+E)) — two rcp fuse
//      into one (rcp(x)*rcp(y) = rcp(x*y)); 5 rcp -> 3 rcp per element.
//      Overflow-safe: exp2 args bounded ~18 << 127 for this data.
//  (d) setprio(1) around the act phase (same T5 mechanism that paid in r7's
//      K-loop: favor compute-phase waves over staging waves of other blocks).
__global__ __launch_bounds__(256, 4) void lstm_kernel(
    const float* __restrict__ inputs, const float* __restrict__ hx,
    const float* __restrict__ cx, const unsigned short* __restrict__ Wpk,
    const float* __restrict__ biasc, const float* __restrict__ W_out,
    float* __restrict__ projP)
{
    __shared__ __align__(16) unsigned short Abf[64 * 256];  // 32 KB; reused as Hf f32[64][64]
    __shared__ float Wlds[768];
    const int tid = threadIdx.x;

    // bijective chunked XCD swizzle: halves (2t,2t+1) land on the same XCD
    const int orig = blockIdx.x;
    const int xcd = orig & 7, idx = orig >> 3;
    const int wgid = (xcd < XR ? xcd * (XQ + 1) : XR * (XQ + 1) + (xcd - XR) * XQ) + idx;
    const int tile = wgid >> 1, ch = wgid & 1;
    const int brow = tile * 64;

    const int lane = tid & 63;
    const int w = tid >> 6;                          // wave 0..3
    const int l15 = lane & 15, l4 = lane >> 4;
    const int hl = w * 16 + l15;                     // hcol-local 0..63
    const int hcol = ch * 64 + hl;                   // global 0..127

    // ---- stage A = [inputs | hx] as bf16, XOR-swizzled: 4 passes x 16 rows ----
    {
        const int r0 = tid >> 4, seg = tid & 15;     // 16 rows/pass, 16 segs of 16 k
        #pragma unroll
        for (int p = 0; p < 4; ++p) {
            int r = p * 16 + r0;
            int team = brow + r; if (team >= NUM_TEAMS) team = NUM_TEAMS - 1;
            const float* src = (seg < 8) ? inputs + (size_t)team * 128 + seg * 16
                                         : hx + (size_t)team * 128 + (seg - 8) * 16;
            float4 v0 = *reinterpret_cast<const float4*>(src);
            float4 v1 = *reinterpret_cast<const float4*>(src + 4);
            float4 v2 = *reinterpret_cast<const float4*>(src + 8);
            float4 v3 = *reinterpret_cast<const float4*>(src + 12);
            char* lbw = reinterpret_cast<char*>(Abf);
            int base = r * 512 + seg * 32;
            int swz = (r & 7) << 4;
            uint4 q0, q1;
            q0.x = cvtpk(v0.x, v0.y); q0.y = cvtpk(v0.z, v0.w);
            q0.z = cvtpk(v1.x, v1.y); q0.w = cvtpk(v1.z, v1.w);
            q1.x = cvtpk(v2.x, v2.y); q1.y = cvtpk(v2.z, v2.w);
            q1.z = cvtpk(v3.x, v3.y); q1.w = cvtpk(v3.z, v3.w);
            *reinterpret_cast<uint4*>(lbw + (base ^ swz)) = q0;
            *reinterpret_cast<uint4*>(lbw + ((base + 16) ^ swz)) = q1;
        }
        Wlds[tid] = W_out[tid];
        Wlds[256 + tid] = W_out[256 + tid];
        Wlds[512 + tid] = W_out[512 + tid];
    }

    // B fragment base: group G = ch*4 + w, contiguous 1KB per wave-load
    const unsigned short* bpg = Wpk + (size_t)(ch * 4 + w) * 16384 + lane * 8;
    const float bic = biasc[hcol];                   // -c*bi
    const float bfc = biasc[128 + hcol];             // -c*bf
    const float bgc = biasc[256 + hcol];             // +2c*bg
    const float boc = biasc[384 + hcol];             // -c*bo
    const int swzA = (l15 & 7) << 4;
    const int kf = l4 * 16;
    const char* pArow = reinterpret_cast<const char*>(Abf) + l15 * 512;

    f32x4 acc[4][4] = {};                            // [m][gate], 64 AGPRs

    // prefetch ks=0 B-quads pre-barrier: latency hides under straggler wait.
    // Staging regs are dead here -> peak live set unchanged.
    bf16x8 b0 = *(const bf16x8*)(bpg);
    bf16x8 b1 = *(const bf16x8*)(bpg + 4096);
    bf16x8 b2 = *(const bf16x8*)(bpg + 8192);
    bf16x8 b3 = *(const bf16x8*)(bpg + 12288);

    __syncthreads();

    __builtin_amdgcn_s_setprio(1);                   // favor K-loop waves
    // ks = 0 (B prefetched above)
    {
        const int ko = kf ^ swzA;
        #pragma unroll
        for (int m = 0; m < 4; ++m) {
            bf16x8 af = *(const bf16x8*)(pArow + m * 8192 + ko);
            acc[m][0] = __builtin_amdgcn_mfma_f32_16x16x32_bf16(af, b0, acc[m][0], 0, 0, 0);
            acc[m][1] = __builtin_amdgcn_mfma_f32_16x16x32_bf16(af, b1, acc[m][1], 0, 0, 0);
            acc[m][2] = __builtin_amdgcn_mfma_f32_16x16x32_bf16(af, b2, acc[m][2], 0, 0, 0);
            acc[m][3] = __builtin_amdgcn_mfma_f32_16x16x32_bf16(af, b3, acc[m][3], 0, 0, 0);
        }
    }
    #pragma unroll
    for (int ks = 1; ks < 8; ++ks) {                 // K = 256 in steps of 32
        b0 = *(const bf16x8*)(bpg + ks * 512);
        b1 = *(const bf16x8*)(bpg + 4096 + ks * 512);
        b2 = *(const bf16x8*)(bpg + 8192 + ks * 512);
        b3 = *(const bf16x8*)(bpg + 12288 + ks * 512);
        const int ko = (ks * 64 + kf) ^ swzA;
        #pragma unroll
        for (int m = 0; m < 4; ++m) {
            bf16x8 af = *(const bf16x8*)(pArow + m * 8192 + ko);
            acc[m][0] = __builtin_amdgcn_mfma_f32_16x16x32_bf16(af, b0, acc[m][0], 0, 0, 0);
            acc[m][1] = __builtin_amdgcn_mfma_f32_16x16x32_bf16(af, b1, acc[m][1], 0, 0, 0);
            acc[m][2] = __builtin_amdgcn_mfma_f32_16x16x32_bf16(af, b2, acc[m][2], 0, 0, 0);
            acc[m][3] = __builtin_amdgcn_mfma_f32_16x16x32_bf16(af, b3, acc[m][3], 0, 0, 0);
        }
    }
    __builtin_amdgcn_s_setprio(0);

    // issue cx loads before the barrier (latency hides under barrier wait)
    float cxa[16];
    #pragma unroll
    for (int m = 0; m < 4; ++m)
        #pragma unroll
        for (int j = 0; j < 4; ++j) {
            int team = brow + m * 16 + l4 * 4 + j;
            if (team >= NUM_TEAMS) team = NUM_TEAMS - 1;
            cxa[m * 4 + j] = cx[(size_t)team * 128 + hcol];
        }

    __syncthreads();                                 // all A reads done; LDS becomes Hf

    // ---- activations streamed per-m; h -> swizzled f32 [64][64] over Abf ----
    // C/D layout: col = l15 -> hcol, row = l4*4 + j -> team-local
    // sigmoid(a)*tanh(b) = (E-1)*rcp((1+I)(1+E)): 5 exp2 + 3 rcp per element.
    __builtin_amdgcn_s_setprio(1);
    {
        char* lb = reinterpret_cast<char*>(Abf);
        #pragma unroll
        for (int m = 0; m < 4; ++m) {
            #pragma unroll
            for (int j = 0; j < 4; ++j) {
                float I = exp2_(fmaf(acc[m][0][j], -LOG2E, bic));          // 2^-(i+bi)c
                float F = exp2_(fmaf(acc[m][1][j], -LOG2E, bfc));
                float E = exp2_(fmaf(acc[m][2][j], 2.0f * LOG2E, bgc));    // 2^{2(g+bg)c}
                float O = exp2_(fmaf(acc[m][3][j], -LOG2E, boc));
                float sf = rcp_(1.0f + F);                                  // sigmoid(f)
                float sitg = (E - 1.0f) * rcp_((1.0f + I) * (1.0f + E));    // sig(i)*tanh(g)
                float cn = fmaf(sf, cxa[m * 4 + j], sitg);
                float C = exp2_(cn * (2.0f * LOG2E));
                float hn = (C - 1.0f) * rcp_((1.0f + O) * (1.0f + C));      // sig(o)*tanh(cn)
                int t = m * 16 + l4 * 4 + j;
                *reinterpret_cast<float*>(lb + ((t * 256 + hl * 4) ^ ((t & 7) << 4))) = hn;
            }
        }
    }
    __builtin_amdgcn_s_setprio(0);
    __syncthreads();

    // ---- fused partial proj: 4 threads/team, 16 hcols each, 6 partial outputs ----
    {
        int tl = tid >> 2, sub = tid & 3;            // team-local 0..63, sub 0..3
        const char* lb = reinterpret_cast<const char*>(Abf);
        int hbase = tl * 256 + sub * 64;
        int hswz = (tl & 7) << 4;
        float a0 = 0.f, a1 = 0.f, a2 = 0.f, a3 = 0.f, a4 = 0.f, a5 = 0.f;
        #pragma unroll
        for (int c = 0; c < 4; ++c) {
            f32x4 h4 = *reinterpret_cast<const f32x4*>(lb + ((hbase + c * 16) ^ hswz));
            #pragma unroll
            for (int i = 0; i < 4; ++i) {
                float h = h4[i];
                int col = ch * 64 + sub * 16 + c * 4 + i;    // global hcol 0..127
                a0 += h * Wlds[col];       a1 += h * Wlds[256 + col]; a2 += h * Wlds[512 + col];
                a3 += h * Wlds[128 + col]; a4 += h * Wlds[384 + col]; a5 += h * Wlds[640 + col];
            }
        }
        a0 += __shfl_xor(a0, 1); a1 += __shfl_xor(a1, 1); a2 += __shfl_xor(a2, 1);
        a3 += __shfl_xor(a3, 1); a4 += __shfl_xor(a4, 1); a5 += __shfl_xor(a5, 1);
        a0 += __shfl_xor(a0, 2); a1 += __shfl_xor(a1, 2); a2 += __shfl_xor(a2, 2);
        a3 += __shfl_xor(a3, 2); a4 += __shfl_xor(a4, 2); a5 += __shfl_xor(a5, 2);
        int team = brow + tl;
        if (sub == 0 && team < NUM_TEAMS) {
            float4* o = reinterpret_cast<float4*>(projP + (size_t)team * 16 + ch * 8);
            o[0] = make_float4(a0, a1, a2, a2);      // home partial
            o[1] = make_float4(a3, a4, a5, a5);      // away partial
        }
    }
}

// ---------------- match head: sum half-partials; logits + b_out ; softmax ----------------
// Output coalescing: 12 B/thread routed through 3 KB LDS -> 192 contiguous
// float4 stores per block (vs 3 strided dword stores/thread).
__global__ __launch_bounds__(256) void match_kernel(
    const int* __restrict__ matches, const float* __restrict__ projP,
    const float* __restrict__ b_out, float* __restrict__ out)
{
    __shared__ __align__(16) float ol[768];
    const int t = threadIdx.x;
    int m = blockIdx.x * 256 + t;
    int mm = (m < NUM_MATCHES) ? m : NUM_MATCHES - 1;
    int2 mi = reinterpret_cast<const int2*>(matches)[mm];
    const float4* pp = reinterpret_cast<const float4*>(projP);
    float4 h0 = pp[(size_t)mi.x * 4 + 0];            // half0 home
    float4 h1 = pp[(size_t)mi.x * 4 + 2];            // half1 home
    float4 a0 = pp[(size_t)mi.y * 4 + 1];            // half0 away
    float4 a1 = pp[(size_t)mi.y * 4 + 3];            // half1 away
    float l0 = h0.x + h1.x + a0.x + a1.x + b_out[0];
    float l1 = h0.y + h1.y + a0.y + a1.y + b_out[1];
    float l2 = h0.z + h1.z + a0.z + a1.z + b_out[2];
    float mx = fmaxf(l0, fmaxf(l1, l2));
    float e0 = __expf(l0 - mx), e1 = __expf(l1 - mx), e2 = __expf(l2 - mx);
    float inv = 1.0f / (e0 + e1 + e2);
    ol[t * 3 + 0] = e0 * inv;                        // stride-3 words: gcd(3,32)=1, 2-way max
    ol[t * 3 + 1] = e1 * inv;
    ol[t * 3 + 2] = e2 * inv;
    __syncthreads();
    if (t < 192) {
        size_t fi = (size_t)blockIdx.x * 192 + t;    // float4 index; 3*NUM_MATCHES/4 = 750000
        if (fi < 750000)
            reinterpret_cast<float4*>(out)[fi] = reinterpret_cast<const float4*>(ol)[t];
    }
}

extern "C" void kernel_launch(void* const* d_in, const int* in_sizes, int n_in,
                              void* d_out, int out_size, void* d_ws, size_t ws_size,
                              hipStream_t stream) {
    const float* inputs = (const float*)d_in[0];
    const float* hx     = (const float*)d_in[1];
    const float* cx     = (const float*)d_in[2];
    const int*   matches= (const int*)d_in[3];
    const float* W_ih   = (const float*)d_in[4];
    const float* W_hh   = (const float*)d_in[5];
    const float* b_ih   = (const float*)d_in[6];
    const float* b_hh   = (const float*)d_in[7];
    const float* W_out  = (const float*)d_in[8];
    const float* b_out  = (const float*)d_in[9];
    float* out = (float*)d_out;

    char* ws = (char*)d_ws;
    unsigned short* Wpk  = (unsigned short*)ws;                  // 256 KB fragment-major
    float* biasc         = (float*)(ws + 262144);                // 2 KB
    float* projP         = (float*)(ws + (1 << 20));             // 100000*16*4 = 6.4 MB

    prep_kernel <<<512, 256, 0, stream>>>(W_ih, W_hh, b_ih, b_hh, Wpk, biasc);
    lstm_kernel <<<NWG, 256, 0, stream>>>(inputs, hx, cx, Wpk, biasc, W_out, projP);
    match_kernel<<<(NUM_MATCHES + 255) / 256, 256, 0, stream>>>(matches, projP, b_out, out);
}

// Round 9
// 78.518 us; speedup vs baseline: 1.0154x; 1.0154x over previous
//
#include <hip/hip_runtime.h>
#include <hip/hip_bf16.h>

typedef __bf16 bf16x8 __attribute__((ext_vector_type(8)));
typedef float f32x4 __attribute__((ext_vector_type(4)));

#define NUM_TEAMS 100000
#define NUM_MATCHES 1000000
#define LOG2E 1.4426950408889634f
#define NWG 3126            // 1563 team-tiles x 2 hcol-halves
#define XQ 390              // NWG/8
#define XR 6                // NWG%8

__device__ __forceinline__ unsigned short f2bf(float x) {
    __hip_bfloat16 h = __float2bfloat16(x);
    return reinterpret_cast<unsigned short&>(h);
}
// single-instruction packed f32x2 -> bf16x2. No builtin on gfx950 (m240) -> asm.
__device__ __forceinline__ unsigned int cvtpk(float a, float b) {
    unsigned int r;
    asm("v_cvt_pk_bf16_f32 %0, %1, %2" : "=v"(r) : "v"(a), "v"(b));
    return r;
}
__device__ __forceinline__ float exp2_(float x) {
    float r; asm("v_exp_f32 %0, %1" : "=v"(r) : "v"(x)); return r;
}
__device__ __forceinline__ float rcp_(float x) {
    float r; asm("v_rcp_f32 %0, %1" : "=v"(r) : "v"(x)); return r;
}

// ---------------- prep: pack W fragment-major bf16; biases pre-scaled by log2e ----------------
// Wpk u16 index = G*16384 + gate*4096 + ks*512 + l4*128 + l15*8 + e
//   holds W[row = gate*128 + G*16 + l15][k = ks*32 + l4*8 + e]  (W = [W_ih | W_hh])
__global__ __launch_bounds__(256) void prep_kernel(
    const float* __restrict__ W_ih, const float* __restrict__ W_hh,
    const float* __restrict__ b_ih, const float* __restrict__ b_hh,
    unsigned short* __restrict__ Wpk, float* __restrict__ biasc)
{
    int gid = blockIdx.x * 256 + threadIdx.x;   // 131072 bf16 elements
    int e = gid & 7;
    int chunk = gid >> 3;                        // 16B chunk id
    int l15 = chunk & 15;
    int l4 = (chunk >> 4) & 3;
    int rest = chunk >> 6;
    int ks = rest & 7;
    int gate = (rest >> 3) & 3;
    int G = rest >> 5;
    int row = gate * 128 + G * 16 + l15;
    int k = ks * 32 + l4 * 8 + e;
    float v = (k < 128) ? W_ih[row * 128 + k] : W_hh[row * 128 + (k - 128)];
    Wpk[gid] = f2bf(v);
    if (gid < 512) {
        float b = b_ih[gid] + b_hh[gid];
        float scale = ((gid >> 7) == 2) ? (2.0f * LOG2E) : (-LOG2E);
        biasc[gid] = b * scale;
    }
}

// ---------------- LSTM + fused partial proj ----------------
// Round-8 skeleton (best lstm counters: 4 blocks/CU, 16 waves/CU, 64 VGPR +
// 64 AGPR = exactly 128/wave). Round-9 change, the last latency lever inside
// the 64-VGPR envelope:
//  (e) staging deepened 4-pass/4-deep -> 2-pass/8-deep: 128 B/thread in flight
//      (2x MLP), half the exposed HBM round-trips per block. Peak live ~46
//      regs (32 payload + addr/misc) — stays under 64 (r3's 16-deep variant
//      hit VGPR=84 -> 3 waves/SIMD; that, not LDS, was its regression).
__global__ __launch_bounds__(256, 4) void lstm_kernel(
    const float* __restrict__ inputs, const float* __restrict__ hx,
    const float* __restrict__ cx, const unsigned short* __restrict__ Wpk,
    const float* __restrict__ biasc, const float* __restrict__ W_out,
    float* __restrict__ projP)
{
    __shared__ __align__(16) unsigned short Abf[64 * 256];  // 32 KB; reused as Hf f32[64][64]
    __shared__ float Wlds[768];
    const int tid = threadIdx.x;

    // bijective chunked XCD swizzle: halves (2t,2t+1) land on the same XCD
    const int orig = blockIdx.x;
    const int xcd = orig & 7, idx = orig >> 3;
    const int wgid = (xcd < XR ? xcd * (XQ + 1) : XR * (XQ + 1) + (xcd - XR) * XQ) + idx;
    const int tile = wgid >> 1, ch = wgid & 1;
    const int brow = tile * 64;

    const int lane = tid & 63;
    const int w = tid >> 6;                          // wave 0..3
    const int l15 = lane & 15, l4 = lane >> 4;
    const int hl = w * 16 + l15;                     // hcol-local 0..63
    const int hcol = ch * 64 + hl;                   // global 0..127

    // ---- stage A = [inputs | hx] as bf16, XOR-swizzled: 2 passes x 2 rows (8-deep) ----
    {
        const int r0 = tid >> 4, seg = tid & 15;     // rows r0 + {0,16,32,48}; 16 segs of 16 k
        const float* srcb = (seg < 8) ? inputs + seg * 16 : hx + (seg - 8) * 16;
        char* lbw = reinterpret_cast<char*>(Abf);
        const int swz = (r0 & 7) << 4;               // (row&7) invariant under +16
        #pragma unroll
        for (int p = 0; p < 2; ++p) {
            int ra = p * 32 + r0, rb = p * 32 + 16 + r0;
            int ta = brow + ra; if (ta >= NUM_TEAMS) ta = NUM_TEAMS - 1;
            int tb = brow + rb; if (tb >= NUM_TEAMS) tb = NUM_TEAMS - 1;
            const float* sa = srcb + (size_t)ta * 128;
            const float* sb = srcb + (size_t)tb * 128;
            // 8 loads issued back-to-back: 128 B in flight per thread
            float4 a0 = *reinterpret_cast<const float4*>(sa);
            float4 a1 = *reinterpret_cast<const float4*>(sa + 4);
            float4 a2 = *reinterpret_cast<const float4*>(sa + 8);
            float4 a3 = *reinterpret_cast<const float4*>(sa + 12);
            float4 b0v = *reinterpret_cast<const float4*>(sb);
            float4 b1v = *reinterpret_cast<const float4*>(sb + 4);
            float4 b2v = *reinterpret_cast<const float4*>(sb + 8);
            float4 b3v = *reinterpret_cast<const float4*>(sb + 12);
            int basea = ra * 512 + seg * 32;
            int baseb = rb * 512 + seg * 32;
            uint4 q0, q1;
            q0.x = cvtpk(a0.x, a0.y); q0.y = cvtpk(a0.z, a0.w);
            q0.z = cvtpk(a1.x, a1.y); q0.w = cvtpk(a1.z, a1.w);
            q1.x = cvtpk(a2.x, a2.y); q1.y = cvtpk(a2.z, a2.w);
            q1.z = cvtpk(a3.x, a3.y); q1.w = cvtpk(a3.z, a3.w);
            *reinterpret_cast<uint4*>(lbw + (basea ^ swz)) = q0;
            *reinterpret_cast<uint4*>(lbw + ((basea + 16) ^ swz)) = q1;
            q0.x = cvtpk(b0v.x, b0v.y); q0.y = cvtpk(b0v.z, b0v.w);
            q0.z = cvtpk(b1v.x, b1v.y); q0.w = cvtpk(b1v.z, b1v.w);
            q1.x = cvtpk(b2v.x, b2v.y); q1.y = cvtpk(b2v.z, b2v.w);
            q1.z = cvtpk(b3v.x, b3v.y); q1.w = cvtpk(b3v.z, b3v.w);
            *reinterpret_cast<uint4*>(lbw + (baseb ^ swz)) = q0;
            *reinterpret_cast<uint4*>(lbw + ((baseb + 16) ^ swz)) = q1;
        }
        Wlds[tid] = W_out[tid];
        Wlds[256 + tid] = W_out[256 + tid];
        Wlds[512 + tid] = W_out[512 + tid];
    }

    // B fragment base: group G = ch*4 + w, contiguous 1KB per wave-load
    const unsigned short* bpg = Wpk + (size_t)(ch * 4 + w) * 16384 + lane * 8;
    const float bic = biasc[hcol];                   // -c*bi
    const float bfc = biasc[128 + hcol];             // -c*bf
    const float bgc = biasc[256 + hcol];             // +2c*bg
    const float boc = biasc[384 + hcol];             // -c*bo
    const int swzA = (l15 & 7) << 4;
    const int kf = l4 * 16;
    const char* pArow = reinterpret_cast<const char*>(Abf) + l15 * 512;

    f32x4 acc[4][4] = {};                            // [m][gate], 64 AGPRs

    // prefetch ks=0 B-quads pre-barrier: latency hides under straggler wait.
    // Staging regs are dead here -> peak live set unchanged.
    bf16x8 b0 = *(const bf16x8*)(bpg);
    bf16x8 b1 = *(const bf16x8*)(bpg + 4096);
    bf16x8 b2 = *(const bf16x8*)(bpg + 8192);
    bf16x8 b3 = *(const bf16x8*)(bpg + 12288);

    __syncthreads();

    __builtin_amdgcn_s_setprio(1);                   // favor K-loop waves
    // ks = 0 (B prefetched above)
    {
        const int ko = kf ^ swzA;
        #pragma unroll
        for (int m = 0; m < 4; ++m) {
            bf16x8 af = *(const bf16x8*)(pArow + m * 8192 + ko);
            acc[m][0] = __builtin_amdgcn_mfma_f32_16x16x32_bf16(af, b0, acc[m][0], 0, 0, 0);
            acc[m][1] = __builtin_amdgcn_mfma_f32_16x16x32_bf16(af, b1, acc[m][1], 0, 0, 0);
            acc[m][2] = __builtin_amdgcn_mfma_f32_16x16x32_bf16(af, b2, acc[m][2], 0, 0, 0);
            acc[m][3] = __builtin_amdgcn_mfma_f32_16x16x32_bf16(af, b3, acc[m][3], 0, 0, 0);
        }
    }
    #pragma unroll
    for (int ks = 1; ks < 8; ++ks) {                 // K = 256 in steps of 32
        b0 = *(const bf16x8*)(bpg + ks * 512);
        b1 = *(const bf16x8*)(bpg + 4096 + ks * 512);
        b2 = *(const bf16x8*)(bpg + 8192 + ks * 512);
        b3 = *(const bf16x8*)(bpg + 12288 + ks * 512);
        const int ko = (ks * 64 + kf) ^ swzA;
        #pragma unroll
        for (int m = 0; m < 4; ++m) {
            bf16x8 af = *(const bf16x8*)(pArow + m * 8192 + ko);
            acc[m][0] = __builtin_amdgcn_mfma_f32_16x16x32_bf16(af, b0, acc[m][0], 0, 0, 0);
            acc[m][1] = __builtin_amdgcn_mfma_f32_16x16x32_bf16(af, b1, acc[m][1], 0, 0, 0);
            acc[m][2] = __builtin_amdgcn_mfma_f32_16x16x32_bf16(af, b2, acc[m][2], 0, 0, 0);
            acc[m][3] = __builtin_amdgcn_mfma_f32_16x16x32_bf16(af, b3, acc[m][3], 0, 0, 0);
        }
    }
    __builtin_amdgcn_s_setprio(0);

    // issue cx loads before the barrier (latency hides under barrier wait)
    float cxa[16];
    #pragma unroll
    for (int m = 0; m < 4; ++m)
        #pragma unroll
        for (int j = 0; j < 4; ++j) {
            int team = brow + m * 16 + l4 * 4 + j;
            if (team >= NUM_TEAMS) team = NUM_TEAMS - 1;
            cxa[m * 4 + j] = cx[(size_t)team * 128 + hcol];
        }

    __syncthreads();                                 // all A reads done; LDS becomes Hf

    // ---- activations streamed per-m; h -> swizzled f32 [64][64] over Abf ----
    // C/D layout: col = l15 -> hcol, row = l4*4 + j -> team-local
    // sigmoid(a)*tanh(b) = (E-1)*rcp((1+I)(1+E)): 5 exp2 + 3 rcp per element.
    __builtin_amdgcn_s_setprio(1);
    {
        char* lb = reinterpret_cast<char*>(Abf);
        #pragma unroll
        for (int m = 0; m < 4; ++m) {
            #pragma unroll
            for (int j = 0; j < 4; ++j) {
                float I = exp2_(fmaf(acc[m][0][j], -LOG2E, bic));          // 2^-(i+bi)c
                float F = exp2_(fmaf(acc[m][1][j], -LOG2E, bfc));
                float E = exp2_(fmaf(acc[m][2][j], 2.0f * LOG2E, bgc));    // 2^{2(g+bg)c}
                float O = exp2_(fmaf(acc[m][3][j], -LOG2E, boc));
                float sf = rcp_(1.0f + F);                                  // sigmoid(f)
                float sitg = (E - 1.0f) * rcp_((1.0f + I) * (1.0f + E));    // sig(i)*tanh(g)
                float cn = fmaf(sf, cxa[m * 4 + j], sitg);
                float C = exp2_(cn * (2.0f * LOG2E));
                float hn = (C - 1.0f) * rcp_((1.0f + O) * (1.0f + C));      // sig(o)*tanh(cn)
                int t = m * 16 + l4 * 4 + j;
                *reinterpret_cast<float*>(lb + ((t * 256 + hl * 4) ^ ((t & 7) << 4))) = hn;
            }
        }
    }
    __builtin_amdgcn_s_setprio(0);
    __syncthreads();

    // ---- fused partial proj: 4 threads/team, 16 hcols each, 6 partial outputs ----
    {
        int tl = tid >> 2, sub = tid & 3;            // team-local 0..63, sub 0..3
        const char* lb = reinterpret_cast<const char*>(Abf);
        int hbase = tl * 256 + sub * 64;
        int hswz = (tl & 7) << 4;
        float a0 = 0.f, a1 = 0.f, a2 = 0.f, a3 = 0.f, a4 = 0.f, a5 = 0.f;
        #pragma unroll
        for (int c = 0; c < 4; ++c) {
            f32x4 h4 = *reinterpret_cast<const f32x4*>(lb + ((hbase + c * 16) ^ hswz));
            #pragma unroll
            for (int i = 0; i < 4; ++i) {
                float h = h4[i];
                int col = ch * 64 + sub * 16 + c * 4 + i;    // global hcol 0..127
                a0 += h * Wlds[col];       a1 += h * Wlds[256 + col]; a2 += h * Wlds[512 + col];
                a3 += h * Wlds[128 + col]; a4 += h * Wlds[384 + col]; a5 += h * Wlds[640 + col];
            }
        }
        a0 += __shfl_xor(a0, 1); a1 += __shfl_xor(a1, 1); a2 += __shfl_xor(a2, 1);
        a3 += __shfl_xor(a3, 1); a4 += __shfl_xor(a4, 1); a5 += __shfl_xor(a5, 1);
        a0 += __shfl_xor(a0, 2); a1 += __shfl_xor(a1, 2); a2 += __shfl_xor(a2, 2);
        a3 += __shfl_xor(a3, 2); a4 += __shfl_xor(a4, 2); a5 += __shfl_xor(a5, 2);
        int team = brow + tl;
        if (sub == 0 && team < NUM_TEAMS) {
            float4* o = reinterpret_cast<float4*>(projP + (size_t)team * 16 + ch * 8);
            o[0] = make_float4(a0, a1, a2, a2);      // home partial
            o[1] = make_float4(a3, a4, a5, a5);      // away partial
        }
    }
}

// ---------------- match head: sum half-partials; logits + b_out ; softmax ----------------
// Output coalescing: 12 B/thread routed through 3 KB LDS -> 192 contiguous
// float4 stores per block (vs 3 strided dword stores/thread).
__global__ __launch_bounds__(256) void match_kernel(
    const int* __restrict__ matches, const float* __restrict__ projP,
    const float* __restrict__ b_out, float* __restrict__ out)
{
    __shared__ __align__(16) float ol[768];
    const int t = threadIdx.x;
    int m = blockIdx.x * 256 + t;
    int mm = (m < NUM_MATCHES) ? m : NUM_MATCHES - 1;
    int2 mi = reinterpret_cast<const int2*>(matches)[mm];
    const float4* pp = reinterpret_cast<const float4*>(projP);
    float4 h0 = pp[(size_t)mi.x * 4 + 0];            // half0 home
    float4 h1 = pp[(size_t)mi.x * 4 + 2];            // half1 home
    float4 a0 = pp[(size_t)mi.y * 4 + 1];            // half0 away
    float4 a1 = pp[(size_t)mi.y * 4 + 3];            // half1 away
    float l0 = h0.x + h1.x + a0.x + a1.x + b_out[0];
    float l1 = h0.y + h1.y + a0.y + a1.y + b_out[1];
    float l2 = h0.z + h1.z + a0.z + a1.z + b_out[2];
    float mx = fmaxf(l0, fmaxf(l1, l2));
    float e0 = __expf(l0 - mx), e1 = __expf(l1 - mx), e2 = __expf(l2 - mx);
    float inv = 1.0f / (e0 + e1 + e2);
    ol[t * 3 + 0] = e0 * inv;                        // stride-3 words: gcd(3,32)=1, 2-way max
    ol[t * 3 + 1] = e1 * inv;
    ol[t * 3 + 2] = e2 * inv;
    __syncthreads();
    if (t < 192) {
        size_t fi = (size_t)blockIdx.x * 192 + t;    // float4 index; 3*NUM_MATCHES/4 = 750000
        if (fi < 750000)
            reinterpret_cast<float4*>(out)[fi] = reinterpret_cast<const float4*>(ol)[t];
    }
}

extern "C" void kernel_launch(void* const* d_in, const int* in_sizes, int n_in,
                              void* d_out, int out_size, void* d_ws, size_t ws_size,
                              hipStream_t stream) {
    const float* inputs = (const float*)d_in[0];
    const float* hx     = (const float*)d_in[1];
    const float* cx     = (const float*)d_in[2];
    const int*   matches= (const int*)d_in[3];
    const float* W_ih   = (const float*)d_in[4];
    const float* W_hh   = (const float*)d_in[5];
    const float* b_ih   = (const float*)d_in[6];
    const float* b_hh   = (const float*)d_in[7];
    const float* W_out  = (const float*)d_in[8];
    const float* b_out  = (const float*)d_in[9];
    float* out = (float*)d_out;

    char* ws = (char*)d_ws;
    unsigned short* Wpk  = (unsigned short*)ws;                  // 256 KB fragment-major
    float* biasc         = (float*)(ws + 262144);                // 2 KB
    float* projP         = (float*)(ws + (1 << 20));             // 100000*16*4 = 6.4 MB

    prep_kernel <<<512, 256, 0, stream>>>(W_ih, W_hh, b_ih, b_hh, Wpk, biasc);
    lstm_kernel <<<NWG, 256, 0, stream>>>(inputs, hx, cx, Wpk, biasc, W_out, projP);
    match_kernel<<<(NUM_MATCHES + 255) / 256, 256, 0, stream>>>(matches, projP, b_out, out);
}